// Round 21
// baseline (244.654 us; speedup 1.0000x reference)
//
#include <hip/hip_runtime.h>
#include <math.h>

// ---------------------------------------------------------------------------
// SheafGNN forward. R33 = R32 (227.1us) + out-GEMM FUSED into conv1 epilogue:
//  - conv1's epilogue holds the full h-row (r1/r2 across 64 lanes). Pack it
//    bf16 into (dead) ms LDS, wave_sync, lane l dots against WTout row l
//    (prep-packed transpose, contiguous 128 u16, L2-hot 16KB) via 64
//    v_dot2_f32_bf16, writes out[v*64+l] (coalesced). conv1 skips xoutb.
//    Deletes: 1 dispatch + gap (~5-8us, R30-measured), 5MB xoutb write,
//    5MB re-read. Epilogue-only -> no loop VGPR growth (R29 lesson).
//  - 7 -> 6 dispatches.
// Pinned: bucket CSR; Pb/Qb split; h0+fill merge; 1-wave WGs; xs dbuf +
// counted vmcnt; lgkm fences; 32-lane expm spread; dot2 aggregation;
// A-reuse GEMM; bf16-only activations; VGPR 68.
// ---------------------------------------------------------------------------

using short8 = __attribute__((ext_vector_type(8))) short;
using f32x4 = __attribute__((ext_vector_type(4))) float;
typedef unsigned short u16;

__device__ __forceinline__ u16 f2bf(float f) {  // RNE fp32->bf16
  unsigned u = __float_as_uint(f);
  unsigned r = (u + 0x7FFFu + ((u >> 16) & 1u)) >> 16;
  return (u16)r;
}
__device__ __forceinline__ float bf2f(u16 v) {
  return __uint_as_float(((unsigned)v) << 16);
}

// per-wave LDS fence (1-wave block): orders ds_write -> ds_read without
// draining vmcnt (keeps global_load_lds prefetches in flight).
__device__ __forceinline__ void wave_sync() {
  __builtin_amdgcn_sched_barrier(0);
  asm volatile("s_waitcnt lgkmcnt(0)" ::: "memory");
  __builtin_amdgcn_sched_barrier(0);
}

// async 16B/lane global->LDS: HW dest = lds_base + lane*16 (wave-uniform
// base); global src is per-lane. Tracked by vmcnt.
__device__ __forceinline__ void glds16(const void* g, void* l) {
  __builtin_amdgcn_global_load_lds(
      (const __attribute__((address_space(1))) unsigned int*)g,
      (__attribute__((address_space(3))) unsigned int*)l, 16, 0, 0);
}

// packed bf16 dot2-accumulate: acc += a.lo*b.lo + a.hi*b.hi (fp32 accum)
__device__ __forceinline__ void dot2bf(float& acc, unsigned a, unsigned b) {
  asm("v_dot2_f32_bf16 %0, %1, %2, %0" : "+v"(acc) : "v"(a), "v"(b));
}

// ---- fused one-time prep: x->bf16, cnt/bucket zero, weight packs, bias -----
__global__ void __launch_bounds__(256) k_prep(const float* __restrict__ x,
    u16* __restrict__ Xb, int* __restrict__ cnt, int n4, int N,
    const float* __restrict__ win, const float* __restrict__ w1a,
    const float* __restrict__ w1b, const float* __restrict__ wout,
    const float* __restrict__ w2a, const float* __restrict__ w2b,
    const float* __restrict__ b1a, const float* __restrict__ b1b,
    u16* __restrict__ WTin, u16* __restrict__ WT1a, u16* __restrict__ WT1b,
    u16* __restrict__ WTout, u16* __restrict__ W2Ta, u16* __restrict__ W2Tb,
    float* __restrict__ B1pa, float* __restrict__ B1pb,
    unsigned* __restrict__ bucket32) {
  int idx = blockIdx.x * 256 + threadIdx.x;
  if (idx < N) cnt[idx] = 0;
  if (idx < N * 32) bucket32[idx] = 0;  // pad rows -> node 0 (valid, unused)
  if (idx < n4) {
    float4 v = ((const float4*)x)[idx];
    ushort4 o;
    o.x = f2bf(v.x);
    o.y = f2bf(v.y);
    o.z = f2bf(v.z);
    o.w = f2bf(v.w);
    ((ushort4*)Xb)[idx] = o;
  }
  if (idx < 16384) {
    int o = idx >> 7, i = idx & 127;
    WTin[idx] = f2bf(win[i * 128 + o]);
  } else if (idx < 32768) {
    int j = idx - 16384;
    int o = j >> 7, i = j & 127;
    WT1a[j] = f2bf(o < 64 ? w1a[i * 64 + o] : w1a[(128 + i) * 64 + (o - 64)]);
  } else if (idx < 49152) {
    int j = idx - 32768;
    int o = j >> 7, i = j & 127;
    WT1b[j] = f2bf(o < 64 ? w1b[i * 64 + o] : w1b[(128 + i) * 64 + (o - 64)]);
  } else if (idx < 57344) {
    int j = idx - 49152;
    int o = j >> 7, i = j & 127;  // o < 64
    WTout[j] = f2bf(wout[i * 64 + o]);
  } else if (idx < 59392) {
    int j = idx - 57344;
    int o = j >> 6, k = j & 63;  // W2T[o][k] = w2[k][o]
    W2Ta[j] = f2bf(w2a[k * 32 + o]);
  } else if (idx < 61440) {
    int j = idx - 59392;
    int o = j >> 6, k = j & 63;
    W2Tb[j] = f2bf(w2b[k * 32 + o]);
  } else if (idx < 61568) {
    int j = idx - 61440;
    B1pa[j] = (j < 64) ? 0.f : b1a[j - 64];
  } else if (idx < 61696) {
    int j = idx - 61568;
    B1pb[j] = (j < 64) ? 0.f : b1b[j - 64];
  }
}

// ---- bf16 MFMA GEMM: wave = 16 rows, loops P/32 col-tiles ------------------
// Split-epilogue mode (Cb2 != null): col<64 -> Cb, col>=64 -> Cb2 (stride 64).
__global__ void __launch_bounds__(256) k_gemm_mfma(const u16* __restrict__ Ab,
    const u16* __restrict__ WT, const float* __restrict__ bias,
    u16* __restrict__ Cb, u16* __restrict__ Cb2, int N, int P) {
  int t = threadIdx.x;
  int wv = t >> 6, lane = t & 63;
  int row0 = (blockIdx.x << 6) + (wv << 4);
  int col = lane & 15, quad = lane >> 4;
  const u16* ar = Ab + (size_t)(row0 + col) * 128 + quad * 8;
  short8 a0 = *(const short8*)(ar);
  short8 a1 = *(const short8*)(ar + 32);
  short8 a2 = *(const short8*)(ar + 64);
  short8 a3 = *(const short8*)(ar + 96);
  int tiles = P >> 5;
  int ct0 = blockIdx.y * tiles;
  for (int ct = 0; ct < tiles; ++ct) {
    int cb = (ct0 + ct) << 4;
    const u16* wrow = WT + (size_t)(cb + col) * 128 + quad * 8;
    short8 b0 = *(const short8*)(wrow);
    short8 b1 = *(const short8*)(wrow + 32);
    short8 b2 = *(const short8*)(wrow + 64);
    short8 b3 = *(const short8*)(wrow + 96);
    float bv = bias ? bias[cb + col] : 0.f;
    f32x4 acc = {0.f, 0.f, 0.f, 0.f};
    acc = __builtin_amdgcn_mfma_f32_16x16x32_bf16(a0, b0, acc, 0, 0, 0);
    acc = __builtin_amdgcn_mfma_f32_16x16x32_bf16(a1, b1, acc, 0, 0, 0);
    acc = __builtin_amdgcn_mfma_f32_16x16x32_bf16(a2, b2, acc, 0, 0, 0);
    acc = __builtin_amdgcn_mfma_f32_16x16x32_bf16(a3, b3, acc, 0, 0, 0);
#pragma unroll
    for (int r = 0; r < 4; ++r) {
      int row = row0 + quad * 4 + r;
      if (row < N) {
        float o = acc[r] + bv;
        int cc = cb + col;
        if (!Cb2) {
          Cb[(size_t)row * 128 + cc] = f2bf(o);
        } else if (cc < 64) {
          Cb[(size_t)row * 64 + cc] = f2bf(o);
        } else {
          Cb2[(size_t)row * 64 + (cc - 64)] = f2bf(o);
        }
      }
    }
  }
}

// ---- MERGED: h0-GEMM (blocks [0,2gN)) + bucket fill (blocks >= 2gN) --------
__global__ void __launch_bounds__(256) k_h0_fill(const u16* __restrict__ Ab,
    const u16* __restrict__ WT, const float* __restrict__ bias,
    u16* __restrict__ Cb, int N, int gN,
    const int* __restrict__ eidx, int* __restrict__ cnt,
    u16* __restrict__ bucket, int E) {
  int b = blockIdx.x;
  if (b < 2 * gN) {
    int t = threadIdx.x;
    int wv = t >> 6, lane = t & 63;
    int bx = (b < gN) ? b : (b - gN);
    int by = (b < gN) ? 0 : 1;
    int row0 = (bx << 6) + (wv << 4);
    int col = lane & 15, quad = lane >> 4;
    const u16* ar = Ab + (size_t)(row0 + col) * 128 + quad * 8;
    short8 a0 = *(const short8*)(ar);
    short8 a1 = *(const short8*)(ar + 32);
    short8 a2 = *(const short8*)(ar + 64);
    short8 a3 = *(const short8*)(ar + 96);
    int ct0 = by * 4;
    for (int ct = 0; ct < 4; ++ct) {
      int cb = (ct0 + ct) << 4;
      const u16* wrow = WT + (size_t)(cb + col) * 128 + quad * 8;
      short8 b0 = *(const short8*)(wrow);
      short8 b1 = *(const short8*)(wrow + 32);
      short8 b2 = *(const short8*)(wrow + 64);
      short8 b3 = *(const short8*)(wrow + 96);
      float bv = bias[cb + col];
      f32x4 acc = {0.f, 0.f, 0.f, 0.f};
      acc = __builtin_amdgcn_mfma_f32_16x16x32_bf16(a0, b0, acc, 0, 0, 0);
      acc = __builtin_amdgcn_mfma_f32_16x16x32_bf16(a1, b1, acc, 0, 0, 0);
      acc = __builtin_amdgcn_mfma_f32_16x16x32_bf16(a2, b2, acc, 0, 0, 0);
      acc = __builtin_amdgcn_mfma_f32_16x16x32_bf16(a3, b3, acc, 0, 0, 0);
#pragma unroll
      for (int r = 0; r < 4; ++r) {
        int row = row0 + quad * 4 + r;
        if (row < N) {
          Cb[(size_t)row * 128 + cb + col] = f2bf(acc[r] + bv);
        }
      }
    }
  } else {
    int e = (b - 2 * gN) * 256 + threadIdx.x;
    if (e >= E) return;
    int r = eidx[e], c = eidx[E + e];
    int pos = atomicAdd(&cnt[c], 1);
    if (pos < 64) bucket[(size_t)c * 64 + pos] = (u16)r;
  }
}

// ---- exact expm of antisym 4x4 via so(4) = su(2) + su(2) -------------------
__device__ __forceinline__ void so4_expm(const float* __restrict__ m,
                                         float* __restrict__ F) {
  float v1 = m[1] - m[4], v2 = m[2] - m[8], v3 = m[3] - m[12];
  float w1 = m[11] - m[14], w2 = m[13] - m[7], w3 = m[6] - m[9];
  float p1 = 0.5f * (v1 + w1), p2 = 0.5f * (v2 + w2), p3 = 0.5f * (v3 + w3);
  float q1 = 0.5f * (v1 - w1), q2 = 0.5f * (v2 - w2), q3 = 0.5f * (v3 - w3);
  float tp2 = p1 * p1 + p2 * p2 + p3 * p3;
  float tq2 = q1 * q1 + q2 * q2 + q3 * q3;
  float tp = sqrtf(tp2), tq = sqrtf(tq2);
  float cp = __cosf(tp);
  float sp = (tp > 1e-6f) ? (__sinf(tp) / tp) : (1.f - tp2 * (1.f / 6.f));
  float cq = __cosf(tq);
  float sq = (tq > 1e-6f) ? (__sinf(tq) / tq) : (1.f - tq2 * (1.f / 6.f));
  float a1 = sp * p1, a2 = sp * p2, a3 = sp * p3;
  float b1 = sq * q1, b2 = sq * q2, b3 = sq * q3;
  float Rp[16] = {cp,  a1,  a2,  a3,  -a1, cp,  a3,  -a2,
                  -a2, -a3, cp,  a1,  -a3, a2,  -a1, cp};
  float Rq[16] = {cq,  b1,  b2,  b3,  -b1, cq,  -b3, b2,
                  -b2, b3,  cq,  -b1, -b3, -b2, b1,  cq};
#pragma unroll
  for (int a = 0; a < 4; ++a)
#pragma unroll
    for (int b = 0; b < 4; ++b) {
      float s = 0.f;
#pragma unroll
      for (int c = 0; c < 4; ++c) s = fmaf(Rp[a * 4 + c], Rq[c * 4 + b], s);
      F[a * 4 + b] = s;
    }
}

// ---- fused conv: one node per single-wave block, bucket entry + prefetch ---
// If wtout != null (last layer): epilogue fuses out = h @ Wout + b via
// LDS row-pack + 64 dot2/lane, writes outf; skips xoutb.
__global__ void __launch_bounds__(64) k_conv(
    const u16* __restrict__ xgb, const u16* __restrict__ pb,
    const u16* __restrict__ qb,
    const u16* __restrict__ W2T, const float* __restrict__ b2,
    const int* __restrict__ deg, const u16* __restrict__ bucket,
    const float* __restrict__ epsp,
    u16* __restrict__ xoutb,
    const u16* __restrict__ wtout, const float* __restrict__ outb,
    float* __restrict__ outf, int N) {
  __shared__ float ms[16 * 44];
  __shared__ u16 xs[2][16 * 128];  // staged xgb rows, double-buffered
  int lane = threadIdx.x;
  int v = blockIdx.x;
  if (v >= N) return;
  int el = lane & 15, quad = lane >> 4;
  // first-batch edge rows + degree: direct-addressed, issue in parallel
  int row = (int)bucket[(size_t)v * 64 + el];
  int dg = deg[v];
  if (dg > 64) dg = 64;
  int a = lane & 3, kb = lane & ~3;
  int xsub = lane >> 4;            // staging: row within 4-row group
  int xcol = (lane & 15) * 8;      // staging: u16 col offset (16B)
  // B-frags: w2^T, wave-invariant. B[n][k=quad*8+j].
  short8 bf00 = *(const short8*)(W2T + (size_t)el * 64 + quad * 8);
  short8 bf01 = *(const short8*)(W2T + (size_t)el * 64 + 32 + quad * 8);
  short8 bf10 = *(const short8*)(W2T + (size_t)(16 + el) * 64 + quad * 8);
  short8 bf11 = *(const short8*)(W2T + (size_t)(16 + el) * 64 + 32 + quad * 8);
  float b2a = b2[el], b2b = b2[16 + el];
  // q-part of h: col == v for every edge of this node -> uniform
  short8 qv0 = *(const short8*)(qb + (size_t)v * 64 + quad * 8);
  short8 qv1 = *(const short8*)(qb + (size_t)v * 64 + 32 + quad * 8);
  // self row: packed bf16 only; fp32 conversion deferred to epilogue
  ushort4 xu1 = *(const ushort4*)(xgb + (size_t)v * 128 + kb);
  ushort4 xu2 = *(const ushort4*)(xgb + (size_t)v * 128 + 64 + kb);
  float s10 = 0.f, s11 = 0.f, s12 = 0.f, s13 = 0.f;  // sum of M1 row a
  float acc1 = 0.f, acc2 = 0.f;  // += (-M2).x_r accumulated via dot2
  int cur = 0;
  if (dg > 0) {  // prologue: stage batch 0's x-rows (bucket-derived, early)
#pragma unroll
    for (int t = 0; t < 4; ++t) {
      int r = __shfl(row, (t << 2) + xsub);
      glds16(xgb + (size_t)r * 128 + xcol, &xs[0][t * 512]);
    }
  }
  for (int b0 = 0; b0 < dg; b0 += 16) {
    int nb = dg - b0;
    nb = (nb > 16) ? 16 : nb;
    int have_next = (b0 + 16 < dg);
    int row_n = row;
    if (have_next) {  // next batch rows from bucket (direct u16)
      int nb2 = dg - b0 - 16;
      nb2 = (nb2 > 16) ? 16 : nb2;
      int ee2 = b0 + 16 + ((el < nb2) ? el : (nb2 - 1));
      row_n = (int)bucket[(size_t)v * 64 + ee2];
    }
    f32x4 c0 = {0.f, 0.f, 0.f, 0.f};
    f32x4 c1 = {0.f, 0.f, 0.f, 0.f};
    {  // k-chunk 0 (feats 0..31); b1 pre-folded into q via GEMM bias
      short8 pv = *(const short8*)(pb + (size_t)row * 64 + quad * 8);
      union { short8 s; unsigned u[4]; } av;
#pragma unroll
      for (int j2 = 0; j2 < 4; ++j2) {
        float h0 = fmaxf(bf2f((u16)pv[2 * j2]) + bf2f((u16)qv0[2 * j2]), 0.f);
        float h1 = fmaxf(
            bf2f((u16)pv[2 * j2 + 1]) + bf2f((u16)qv0[2 * j2 + 1]), 0.f);
        unsigned r;
        asm("v_cvt_pk_bf16_f32 %0, %1, %2" : "=v"(r) : "v"(h0), "v"(h1));
        av.u[j2] = r;
      }
      c0 = __builtin_amdgcn_mfma_f32_16x16x32_bf16(av.s, bf00, c0, 0, 0, 0);
      c1 = __builtin_amdgcn_mfma_f32_16x16x32_bf16(av.s, bf10, c1, 0, 0, 0);
    }
    {  // k-chunk 1 (feats 32..63)
      short8 pv = *(const short8*)(pb + (size_t)row * 64 + 32 + quad * 8);
      union { short8 s; unsigned u[4]; } av;
#pragma unroll
      for (int j2 = 0; j2 < 4; ++j2) {
        float h0 = fmaxf(bf2f((u16)pv[2 * j2]) + bf2f((u16)qv1[2 * j2]), 0.f);
        float h1 = fmaxf(
            bf2f((u16)pv[2 * j2 + 1]) + bf2f((u16)qv1[2 * j2 + 1]), 0.f);
        unsigned r;
        asm("v_cvt_pk_bf16_f32 %0, %1, %2" : "=v"(r) : "v"(h0), "v"(h1));
        av.u[j2] = r;
      }
      c0 = __builtin_amdgcn_mfma_f32_16x16x32_bf16(av.s, bf01, c0, 0, 0, 0);
      c1 = __builtin_amdgcn_mfma_f32_16x16x32_bf16(av.s, bf11, c1, 0, 0, 0);
    }
    // C layout: row(quad*4+r)=edge, col(el)=output. Transpose via LDS.
#pragma unroll
    for (int r = 0; r < 4; ++r) {
      ms[(quad * 4 + r) * 44 + el] = c0[r] + b2a;
      ms[(quad * 4 + r) * 44 + 16 + el] = c1[r] + b2b;
    }
    wave_sync();
    // stage NEXT batch's x-rows while expm+aggregation run
    if (have_next) {
#pragma unroll
      for (int t = 0; t < 4; ++t) {
        int r = __shfl(row_n, (t << 2) + xsub);
        glds16(xgb + (size_t)r * 128 + xcol, &xs[cur ^ 1][t * 512]);
      }
    }
    // expm spread over 32 lanes: lane hi*16+el does ONE so4_expm.
    if (lane < 32) {
      int hi = quad;  // 0: Fu (cols 0..15), 1: Fv (cols 16..31)
      const float* mr = ms + el * 44 + hi * 16;
      float mloc[16];
#pragma unroll
      for (int i = 0; i < 4; ++i)
        *(float4*)(mloc + 4 * i) = *(const float4*)(mr + 4 * i);
      float F[16];
      so4_expm(mloc, F);
      // broadcast Fu (held by lane el) to the whole pair; product is
      // uniform: M = fu^T F (hi=0: M1=Fu^T Fu; hi=1: M2=Fu^T Fv).
      float fu[16];
#pragma unroll
      for (int i = 0; i < 16; ++i) fu[i] = __shfl(F[i], el);
      float res[16];
#pragma unroll
      for (int aa = 0; aa < 4; ++aa)
#pragma unroll
        for (int bb = 0; bb < 4; ++bb) {
          float s = 0.f;
#pragma unroll
          for (int cc = 0; cc < 4; ++cc)
            s = fmaf(fu[cc * 4 + aa], F[cc * 4 + bb], s);
          res[aa * 4 + bb] = s;
        }
      if (hi == 0) {  // M1 fp32 (s-sum epilogue path)
        float* mw = ms + el * 44;
#pragma unroll
        for (int i = 0; i < 4; ++i)
          *(float4*)(mw + 4 * i) = *(const float4*)(res + 4 * i);
      } else {  // -M2 packed bf16 (dot2 aggregation path)
        unsigned* mw32 = (unsigned*)(ms + el * 44 + 16);
#pragma unroll
        for (int w = 0; w < 8; ++w) {
          float lo = -res[2 * w], hi2 = -res[2 * w + 1];
          unsigned r;
          asm("v_cvt_pk_bf16_f32 %0, %1, %2" : "=v"(r) : "v"(lo), "v"(hi2));
          mw32[w] = r;
        }
      }
    }
    wave_sync();
    // X(cur) resident (in-order retirement); counted fence keeps
    // next-batch stage in flight.
    if (have_next) {
      asm volatile("s_waitcnt vmcnt(4)" ::: "memory");
    } else {
      asm volatile("s_waitcnt vmcnt(0)" ::: "memory");
    }
    __builtin_amdgcn_sched_barrier(0);
    const u16* xc = xs[cur];
    int j = 0;
    for (; j + 1 < nb; j += 2) {
      float4 am1 = *(const float4*)(ms + j * 44 + a * 4);
      float4 bm1 = *(const float4*)(ms + (j + 1) * 44 + a * 4);
      // -M2 row a as 2 packed-bf16 words (broadcast across 16 lanes)
      uint2 am2 = *(const uint2*)((const unsigned*)(ms + j * 44 + 16) + a * 2);
      uint2 bm2 =
          *(const uint2*)((const unsigned*)(ms + (j + 1) * 44 + 16) + a * 2);
      uint2 ua1 = *(const uint2*)(xc + j * 128 + kb);
      uint2 ua2 = *(const uint2*)(xc + j * 128 + 64 + kb);
      uint2 ub1 = *(const uint2*)(xc + (j + 1) * 128 + kb);
      uint2 ub2 = *(const uint2*)(xc + (j + 1) * 128 + 64 + kb);
      s10 += am1.x + bm1.x;
      s11 += am1.y + bm1.y;
      s12 += am1.z + bm1.z;
      s13 += am1.w + bm1.w;
      dot2bf(acc1, am2.x, ua1.x);
      dot2bf(acc1, am2.y, ua1.y);
      dot2bf(acc2, am2.x, ua2.x);
      dot2bf(acc2, am2.y, ua2.y);
      dot2bf(acc1, bm2.x, ub1.x);
      dot2bf(acc1, bm2.y, ub1.y);
      dot2bf(acc2, bm2.x, ub2.x);
      dot2bf(acc2, bm2.y, ub2.y);
    }
    if (j < nb) {
      float4 am1 = *(const float4*)(ms + j * 44 + a * 4);
      uint2 am2 = *(const uint2*)((const unsigned*)(ms + j * 44 + 16) + a * 2);
      uint2 ua1 = *(const uint2*)(xc + j * 128 + kb);
      uint2 ua2 = *(const uint2*)(xc + j * 128 + 64 + kb);
      s10 += am1.x;
      s11 += am1.y;
      s12 += am1.z;
      s13 += am1.w;
      dot2bf(acc1, am2.x, ua1.x);
      dot2bf(acc1, am2.y, ua1.y);
      dot2bf(acc2, am2.x, ua2.x);
      dot2bf(acc2, am2.y, ua2.y);
    }
    wave_sync();  // ms + xs[cur] reused next batch (WAR)
    row = row_n;
    cur ^= 1;
  }
  // epilogue: convert self row from the still-live packed regs (no loads)
  float4 xi1 =
      make_float4(bf2f(xu1.x), bf2f(xu1.y), bf2f(xu1.z), bf2f(xu1.w));
  float4 xi2 =
      make_float4(bf2f(xu2.x), bf2f(xu2.y), bf2f(xu2.z), bf2f(xu2.w));
  float hv1 = (a == 0) ? xi1.x : (a == 1) ? xi1.y : (a == 2) ? xi1.z : xi1.w;
  float hv2 = (a == 0) ? xi2.x : (a == 1) ? xi2.y : (a == 2) ? xi2.z : xi2.w;
  acc1 += s10 * xi1.x + s11 * xi1.y + s12 * xi1.z + s13 * xi1.w;
  acc2 += s10 * xi2.x + s11 * xi2.y + s12 * xi2.z + s13 * xi2.w;
  float eps = *epsp;
  float r1 = hv1 - eps * acc1;
  float r2 = hv2 - eps * acc2;
  r1 = (r1 > 0.f) ? r1 : expm1f(r1);
  r2 = (r2 > 0.f) ? r2 : expm1f(r2);
  if (wtout) {
    // fused out = h @ Wout + b: pack h-row bf16 into (dead) ms LDS,
    // lane l dots against WTout row l (contiguous 128 u16, L2-hot).
    u16* hrow = (u16*)ms;
    hrow[lane] = f2bf(r1);
    hrow[64 + lane] = f2bf(r2);
    wave_sync();
    const unsigned* hr32 = (const unsigned*)hrow;
    const u16* wr = wtout + (size_t)lane * 128;
    float acc = outb[lane];
#pragma unroll
    for (int w = 0; w < 16; ++w) {
      short8 wv = *(const short8*)(wr + w * 8);
      union { short8 s; unsigned u[4]; } wu;
      wu.s = wv;
      dot2bf(acc, hr32[w * 4 + 0], wu.u[0]);
      dot2bf(acc, hr32[w * 4 + 1], wu.u[1]);
      dot2bf(acc, hr32[w * 4 + 2], wu.u[2]);
      dot2bf(acc, hr32[w * 4 + 3], wu.u[3]);
    }
    outf[(size_t)v * 64 + lane] = acc;
  } else {
    xoutb[(size_t)v * 128 + lane] = f2bf(r1);
    xoutb[(size_t)v * 128 + 64 + lane] = f2bf(r2);
  }
}

extern "C" void kernel_launch(void* const* d_in, const int* in_sizes, int n_in,
                              void* d_out, int out_size, void* d_ws,
                              size_t ws_size, hipStream_t stream) {
  const float* x = (const float*)d_in[0];
  const int* eidx = (const int*)d_in[1];
  const float* lin_in_w = (const float*)d_in[2];
  const float* lin_in_b = (const float*)d_in[3];
  const float* c0w1 = (const float*)d_in[4];
  const float* c0b1 = (const float*)d_in[5];
  const float* c0w2 = (const float*)d_in[6];
  const float* c0b2 = (const float*)d_in[7];
  const float* c0eps = (const float*)d_in[8];
  const float* c1w1 = (const float*)d_in[9];
  const float* c1b1 = (const float*)d_in[10];
  const float* c1w2 = (const float*)d_in[11];
  const float* c1b2 = (const float*)d_in[12];
  const float* c1eps = (const float*)d_in[13];
  const float* lout_w = (const float*)d_in[14];
  const float* lout_b = (const float*)d_in[15];
  float* out = (float*)d_out;

  int N = in_sizes[0] / 128;
  int E = in_sizes[1] / 2;
  int Npad = N + 64;

  char* ws = (char*)d_ws;
  size_t szHb = (size_t)Npad * 128 * 2;
  size_t szPb = (size_t)Npad * 64 * 2;
  u16* Xb = (u16*)ws;
  u16* Hb = (u16*)(ws + szHb);
  u16* H2b = (u16*)(ws + 2 * szHb);
  u16* Pb = (u16*)(ws + 3 * szHb);
  u16* Qb = (u16*)(ws + 3 * szHb + szPb);
  u16* WTin = (u16*)(ws + 3 * szHb + 2 * szPb);
  u16* WT1a = WTin + 16384;
  u16* WT1b = WT1a + 16384;
  u16* WTout = WT1b + 16384;
  u16* W2Ta = WTout + 8192;
  u16* W2Tb = W2Ta + 2048;
  float* B1pa = (float*)(W2Tb + 2048);
  float* B1pb = B1pa + 128;
  char* ip = (char*)(B1pb + 128);
  int* cnt = (int*)ip;                                  // N
  u16* bucket = (u16*)(ip + 4 * (size_t)(N + 64));      // N*64 u16

  dim3 blk(256);
  int gN = (N + 63) / 64;
  int gE = (E + 255) / 256;

  // fused prep
  k_prep<<<(N * 32 + 255) / 256, blk, 0, stream>>>(
      x, Xb, cnt, N * 32, N, lin_in_w, c0w1, c1w1, lout_w, c0w2, c1w2, c0b1,
      c1b1, WTin, WT1a, WT1b, WTout, W2Ta, W2Tb, B1pa, B1pb,
      (unsigned*)bucket);

  // MERGED: h0 GEMM (2*gN blocks) + bucket fill (gE blocks)
  k_h0_fill<<<2 * gN + gE, blk, 0, stream>>>(Xb, WTin, lin_in_b, Hb, N, gN,
                                             eidx, cnt, bucket, E);

  u16* curb = Hb;
  u16* nxtb = H2b;
  for (int layer = 0; layer < 2; ++layer) {
    const u16* wt1 = layer ? WT1b : WT1a;
    const u16* w2t = layer ? W2Tb : W2Ta;
    const float* b1p = layer ? B1pb : B1pa;
    const float* b2 = layer ? c1b2 : c0b2;
    const float* ep = layer ? c1eps : c0eps;
    // pq = h @ W1p + [0|b1]  (split epilogue: Pb dense 2.5MB + Qb)
    k_gemm_mfma<<<dim3(gN, 2), blk, 0, stream>>>(curb, wt1, b1p, Pb, Qb, N,
                                                 128);
    if (layer == 0) {
      k_conv<<<N, dim3(64), 0, stream>>>(curb, Pb, Qb, w2t, b2, cnt, bucket,
                                         ep, nxtb, nullptr, nullptr, nullptr,
                                         N);
    } else {
      // last layer: out-GEMM fused into the conv epilogue
      k_conv<<<N, dim3(64), 0, stream>>>(curb, Pb, Qb, w2t, b2, cnt, bucket,
                                         ep, nullptr, WTout, lout_b, out, N);
    }
    u16* tb = curb; curb = nxtb; nxtb = tb;
  }
}

// Round 22
// 243.471 us; speedup vs baseline: 1.0049x; 1.0049x over previous
//
#include <hip/hip_runtime.h>
#include <math.h>

// ---------------------------------------------------------------------------
// SheafGNN forward. R34 = R32 (227.1us) + out-GEMM fusion RETRIED as a
// SEPARATE kernel clone:
//  - R33 lesson: one kernel serving both layers contaminated codegen --
//    BOTH convs slowed 45->71us (identical loop, VALUBusy 46->34) once the
//    epilogue gained a u16-aliased LDS read + 3 extra args. Fix: k_conv
//    restored VERBATIM from R32 (layer 0, byte-identical codegen);
//    k_conv_out is a clone with the fused out=h@Wout+b epilogue (layer 1).
//  - If k_conv_out also runs ~71us the fusion mechanism is at fault ->
//    revert to R32 next round (pre-registered).
// Pinned: bucket CSR; Pb/Qb split; h0+fill merge; 1-wave WGs; xs dbuf +
// counted vmcnt; lgkm fences; 32-lane expm spread; dot2 aggregation;
// A-reuse GEMM; bf16-only activations; VGPR 68.
// ---------------------------------------------------------------------------

using short8 = __attribute__((ext_vector_type(8))) short;
using f32x4 = __attribute__((ext_vector_type(4))) float;
typedef unsigned short u16;

__device__ __forceinline__ u16 f2bf(float f) {  // RNE fp32->bf16
  unsigned u = __float_as_uint(f);
  unsigned r = (u + 0x7FFFu + ((u >> 16) & 1u)) >> 16;
  return (u16)r;
}
__device__ __forceinline__ float bf2f(u16 v) {
  return __uint_as_float(((unsigned)v) << 16);
}

// per-wave LDS fence (1-wave block): orders ds_write -> ds_read without
// draining vmcnt (keeps global_load_lds prefetches in flight).
__device__ __forceinline__ void wave_sync() {
  __builtin_amdgcn_sched_barrier(0);
  asm volatile("s_waitcnt lgkmcnt(0)" ::: "memory");
  __builtin_amdgcn_sched_barrier(0);
}

// async 16B/lane global->LDS: HW dest = lds_base + lane*16 (wave-uniform
// base); global src is per-lane. Tracked by vmcnt.
__device__ __forceinline__ void glds16(const void* g, void* l) {
  __builtin_amdgcn_global_load_lds(
      (const __attribute__((address_space(1))) unsigned int*)g,
      (__attribute__((address_space(3))) unsigned int*)l, 16, 0, 0);
}

// packed bf16 dot2-accumulate: acc += a.lo*b.lo + a.hi*b.hi (fp32 accum)
__device__ __forceinline__ void dot2bf(float& acc, unsigned a, unsigned b) {
  asm("v_dot2_f32_bf16 %0, %1, %2, %0" : "+v"(acc) : "v"(a), "v"(b));
}

// ---- fused one-time prep: x->bf16, cnt/bucket zero, weight packs, bias -----
__global__ void __launch_bounds__(256) k_prep(const float* __restrict__ x,
    u16* __restrict__ Xb, int* __restrict__ cnt, int n4, int N,
    const float* __restrict__ win, const float* __restrict__ w1a,
    const float* __restrict__ w1b, const float* __restrict__ wout,
    const float* __restrict__ w2a, const float* __restrict__ w2b,
    const float* __restrict__ b1a, const float* __restrict__ b1b,
    u16* __restrict__ WTin, u16* __restrict__ WT1a, u16* __restrict__ WT1b,
    u16* __restrict__ WTout, u16* __restrict__ W2Ta, u16* __restrict__ W2Tb,
    float* __restrict__ B1pa, float* __restrict__ B1pb,
    unsigned* __restrict__ bucket32) {
  int idx = blockIdx.x * 256 + threadIdx.x;
  if (idx < N) cnt[idx] = 0;
  if (idx < N * 32) bucket32[idx] = 0;  // pad rows -> node 0 (valid, unused)
  if (idx < n4) {
    float4 v = ((const float4*)x)[idx];
    ushort4 o;
    o.x = f2bf(v.x);
    o.y = f2bf(v.y);
    o.z = f2bf(v.z);
    o.w = f2bf(v.w);
    ((ushort4*)Xb)[idx] = o;
  }
  if (idx < 16384) {
    int o = idx >> 7, i = idx & 127;
    WTin[idx] = f2bf(win[i * 128 + o]);
  } else if (idx < 32768) {
    int j = idx - 16384;
    int o = j >> 7, i = j & 127;
    WT1a[j] = f2bf(o < 64 ? w1a[i * 64 + o] : w1a[(128 + i) * 64 + (o - 64)]);
  } else if (idx < 49152) {
    int j = idx - 32768;
    int o = j >> 7, i = j & 127;
    WT1b[j] = f2bf(o < 64 ? w1b[i * 64 + o] : w1b[(128 + i) * 64 + (o - 64)]);
  } else if (idx < 57344) {
    int j = idx - 49152;
    int o = j >> 7, i = j & 127;  // o < 64
    WTout[j] = f2bf(wout[i * 64 + o]);
  } else if (idx < 59392) {
    int j = idx - 57344;
    int o = j >> 6, k = j & 63;  // W2T[o][k] = w2[k][o]
    W2Ta[j] = f2bf(w2a[k * 32 + o]);
  } else if (idx < 61440) {
    int j = idx - 59392;
    int o = j >> 6, k = j & 63;
    W2Tb[j] = f2bf(w2b[k * 32 + o]);
  } else if (idx < 61568) {
    int j = idx - 61440;
    B1pa[j] = (j < 64) ? 0.f : b1a[j - 64];
  } else if (idx < 61696) {
    int j = idx - 61568;
    B1pb[j] = (j < 64) ? 0.f : b1b[j - 64];
  }
}

// ---- bf16 MFMA GEMM: wave = 16 rows, loops P/32 col-tiles ------------------
// Split-epilogue mode (Cb2 != null): col<64 -> Cb, col>=64 -> Cb2 (stride 64).
__global__ void __launch_bounds__(256) k_gemm_mfma(const u16* __restrict__ Ab,
    const u16* __restrict__ WT, const float* __restrict__ bias,
    u16* __restrict__ Cb, u16* __restrict__ Cb2, int N, int P) {
  int t = threadIdx.x;
  int wv = t >> 6, lane = t & 63;
  int row0 = (blockIdx.x << 6) + (wv << 4);
  int col = lane & 15, quad = lane >> 4;
  const u16* ar = Ab + (size_t)(row0 + col) * 128 + quad * 8;
  short8 a0 = *(const short8*)(ar);
  short8 a1 = *(const short8*)(ar + 32);
  short8 a2 = *(const short8*)(ar + 64);
  short8 a3 = *(const short8*)(ar + 96);
  int tiles = P >> 5;
  int ct0 = blockIdx.y * tiles;
  for (int ct = 0; ct < tiles; ++ct) {
    int cb = (ct0 + ct) << 4;
    const u16* wrow = WT + (size_t)(cb + col) * 128 + quad * 8;
    short8 b0 = *(const short8*)(wrow);
    short8 b1 = *(const short8*)(wrow + 32);
    short8 b2 = *(const short8*)(wrow + 64);
    short8 b3 = *(const short8*)(wrow + 96);
    float bv = bias ? bias[cb + col] : 0.f;
    f32x4 acc = {0.f, 0.f, 0.f, 0.f};
    acc = __builtin_amdgcn_mfma_f32_16x16x32_bf16(a0, b0, acc, 0, 0, 0);
    acc = __builtin_amdgcn_mfma_f32_16x16x32_bf16(a1, b1, acc, 0, 0, 0);
    acc = __builtin_amdgcn_mfma_f32_16x16x32_bf16(a2, b2, acc, 0, 0, 0);
    acc = __builtin_amdgcn_mfma_f32_16x16x32_bf16(a3, b3, acc, 0, 0, 0);
#pragma unroll
    for (int r = 0; r < 4; ++r) {
      int row = row0 + quad * 4 + r;
      if (row < N) {
        float o = acc[r] + bv;
        int cc = cb + col;
        if (!Cb2) {
          Cb[(size_t)row * 128 + cc] = f2bf(o);
        } else if (cc < 64) {
          Cb[(size_t)row * 64 + cc] = f2bf(o);
        } else {
          Cb2[(size_t)row * 64 + (cc - 64)] = f2bf(o);
        }
      }
    }
  }
}

// ---- MERGED: h0-GEMM (blocks [0,2gN)) + bucket fill (blocks >= 2gN) --------
__global__ void __launch_bounds__(256) k_h0_fill(const u16* __restrict__ Ab,
    const u16* __restrict__ WT, const float* __restrict__ bias,
    u16* __restrict__ Cb, int N, int gN,
    const int* __restrict__ eidx, int* __restrict__ cnt,
    u16* __restrict__ bucket, int E) {
  int b = blockIdx.x;
  if (b < 2 * gN) {
    int t = threadIdx.x;
    int wv = t >> 6, lane = t & 63;
    int bx = (b < gN) ? b : (b - gN);
    int by = (b < gN) ? 0 : 1;
    int row0 = (bx << 6) + (wv << 4);
    int col = lane & 15, quad = lane >> 4;
    const u16* ar = Ab + (size_t)(row0 + col) * 128 + quad * 8;
    short8 a0 = *(const short8*)(ar);
    short8 a1 = *(const short8*)(ar + 32);
    short8 a2 = *(const short8*)(ar + 64);
    short8 a3 = *(const short8*)(ar + 96);
    int ct0 = by * 4;
    for (int ct = 0; ct < 4; ++ct) {
      int cb = (ct0 + ct) << 4;
      const u16* wrow = WT + (size_t)(cb + col) * 128 + quad * 8;
      short8 b0 = *(const short8*)(wrow);
      short8 b1 = *(const short8*)(wrow + 32);
      short8 b2 = *(const short8*)(wrow + 64);
      short8 b3 = *(const short8*)(wrow + 96);
      float bv = bias[cb + col];
      f32x4 acc = {0.f, 0.f, 0.f, 0.f};
      acc = __builtin_amdgcn_mfma_f32_16x16x32_bf16(a0, b0, acc, 0, 0, 0);
      acc = __builtin_amdgcn_mfma_f32_16x16x32_bf16(a1, b1, acc, 0, 0, 0);
      acc = __builtin_amdgcn_mfma_f32_16x16x32_bf16(a2, b2, acc, 0, 0, 0);
      acc = __builtin_amdgcn_mfma_f32_16x16x32_bf16(a3, b3, acc, 0, 0, 0);
#pragma unroll
      for (int r = 0; r < 4; ++r) {
        int row = row0 + quad * 4 + r;
        if (row < N) {
          Cb[(size_t)row * 128 + cb + col] = f2bf(acc[r] + bv);
        }
      }
    }
  } else {
    int e = (b - 2 * gN) * 256 + threadIdx.x;
    if (e >= E) return;
    int r = eidx[e], c = eidx[E + e];
    int pos = atomicAdd(&cnt[c], 1);
    if (pos < 64) bucket[(size_t)c * 64 + pos] = (u16)r;
  }
}

// ---- exact expm of antisym 4x4 via so(4) = su(2) + su(2) -------------------
__device__ __forceinline__ void so4_expm(const float* __restrict__ m,
                                         float* __restrict__ F) {
  float v1 = m[1] - m[4], v2 = m[2] - m[8], v3 = m[3] - m[12];
  float w1 = m[11] - m[14], w2 = m[13] - m[7], w3 = m[6] - m[9];
  float p1 = 0.5f * (v1 + w1), p2 = 0.5f * (v2 + w2), p3 = 0.5f * (v3 + w3);
  float q1 = 0.5f * (v1 - w1), q2 = 0.5f * (v2 - w2), q3 = 0.5f * (v3 - w3);
  float tp2 = p1 * p1 + p2 * p2 + p3 * p3;
  float tq2 = q1 * q1 + q2 * q2 + q3 * q3;
  float tp = sqrtf(tp2), tq = sqrtf(tq2);
  float cp = __cosf(tp);
  float sp = (tp > 1e-6f) ? (__sinf(tp) / tp) : (1.f - tp2 * (1.f / 6.f));
  float cq = __cosf(tq);
  float sq = (tq > 1e-6f) ? (__sinf(tq) / tq) : (1.f - tq2 * (1.f / 6.f));
  float a1 = sp * p1, a2 = sp * p2, a3 = sp * p3;
  float b1 = sq * q1, b2 = sq * q2, b3 = sq * q3;
  float Rp[16] = {cp,  a1,  a2,  a3,  -a1, cp,  a3,  -a2,
                  -a2, -a3, cp,  a1,  -a3, a2,  -a1, cp};
  float Rq[16] = {cq,  b1,  b2,  b3,  -b1, cq,  -b3, b2,
                  -b2, b3,  cq,  -b1, -b3, -b2, b1,  cq};
#pragma unroll
  for (int a = 0; a < 4; ++a)
#pragma unroll
    for (int b = 0; b < 4; ++b) {
      float s = 0.f;
#pragma unroll
      for (int c = 0; c < 4; ++c) s = fmaf(Rp[a * 4 + c], Rq[c * 4 + b], s);
      F[a * 4 + b] = s;
    }
}

// ---- fused conv (layer 0): VERBATIM R32 body -------------------------------
__global__ void __launch_bounds__(64) k_conv(
    const u16* __restrict__ xgb, const u16* __restrict__ pb,
    const u16* __restrict__ qb,
    const u16* __restrict__ W2T, const float* __restrict__ b2,
    const int* __restrict__ deg, const u16* __restrict__ bucket,
    const float* __restrict__ epsp,
    u16* __restrict__ xoutb, int N) {
  __shared__ float ms[16 * 44];
  __shared__ u16 xs[2][16 * 128];  // staged xgb rows, double-buffered
  int lane = threadIdx.x;
  int v = blockIdx.x;
  if (v >= N) return;
  int el = lane & 15, quad = lane >> 4;
  int row = (int)bucket[(size_t)v * 64 + el];
  int dg = deg[v];
  if (dg > 64) dg = 64;
  int a = lane & 3, kb = lane & ~3;
  int xsub = lane >> 4;
  int xcol = (lane & 15) * 8;
  short8 bf00 = *(const short8*)(W2T + (size_t)el * 64 + quad * 8);
  short8 bf01 = *(const short8*)(W2T + (size_t)el * 64 + 32 + quad * 8);
  short8 bf10 = *(const short8*)(W2T + (size_t)(16 + el) * 64 + quad * 8);
  short8 bf11 = *(const short8*)(W2T + (size_t)(16 + el) * 64 + 32 + quad * 8);
  float b2a = b2[el], b2b = b2[16 + el];
  short8 qv0 = *(const short8*)(qb + (size_t)v * 64 + quad * 8);
  short8 qv1 = *(const short8*)(qb + (size_t)v * 64 + 32 + quad * 8);
  ushort4 xu1 = *(const ushort4*)(xgb + (size_t)v * 128 + kb);
  ushort4 xu2 = *(const ushort4*)(xgb + (size_t)v * 128 + 64 + kb);
  float s10 = 0.f, s11 = 0.f, s12 = 0.f, s13 = 0.f;
  float acc1 = 0.f, acc2 = 0.f;
  int cur = 0;
  if (dg > 0) {
#pragma unroll
    for (int t = 0; t < 4; ++t) {
      int r = __shfl(row, (t << 2) + xsub);
      glds16(xgb + (size_t)r * 128 + xcol, &xs[0][t * 512]);
    }
  }
  for (int b0 = 0; b0 < dg; b0 += 16) {
    int nb = dg - b0;
    nb = (nb > 16) ? 16 : nb;
    int have_next = (b0 + 16 < dg);
    int row_n = row;
    if (have_next) {
      int nb2 = dg - b0 - 16;
      nb2 = (nb2 > 16) ? 16 : nb2;
      int ee2 = b0 + 16 + ((el < nb2) ? el : (nb2 - 1));
      row_n = (int)bucket[(size_t)v * 64 + ee2];
    }
    f32x4 c0 = {0.f, 0.f, 0.f, 0.f};
    f32x4 c1 = {0.f, 0.f, 0.f, 0.f};
    {
      short8 pv = *(const short8*)(pb + (size_t)row * 64 + quad * 8);
      union { short8 s; unsigned u[4]; } av;
#pragma unroll
      for (int j2 = 0; j2 < 4; ++j2) {
        float h0 = fmaxf(bf2f((u16)pv[2 * j2]) + bf2f((u16)qv0[2 * j2]), 0.f);
        float h1 = fmaxf(
            bf2f((u16)pv[2 * j2 + 1]) + bf2f((u16)qv0[2 * j2 + 1]), 0.f);
        unsigned r;
        asm("v_cvt_pk_bf16_f32 %0, %1, %2" : "=v"(r) : "v"(h0), "v"(h1));
        av.u[j2] = r;
      }
      c0 = __builtin_amdgcn_mfma_f32_16x16x32_bf16(av.s, bf00, c0, 0, 0, 0);
      c1 = __builtin_amdgcn_mfma_f32_16x16x32_bf16(av.s, bf10, c1, 0, 0, 0);
    }
    {
      short8 pv = *(const short8*)(pb + (size_t)row * 64 + 32 + quad * 8);
      union { short8 s; unsigned u[4]; } av;
#pragma unroll
      for (int j2 = 0; j2 < 4; ++j2) {
        float h0 = fmaxf(bf2f((u16)pv[2 * j2]) + bf2f((u16)qv1[2 * j2]), 0.f);
        float h1 = fmaxf(
            bf2f((u16)pv[2 * j2 + 1]) + bf2f((u16)qv1[2 * j2 + 1]), 0.f);
        unsigned r;
        asm("v_cvt_pk_bf16_f32 %0, %1, %2" : "=v"(r) : "v"(h0), "v"(h1));
        av.u[j2] = r;
      }
      c0 = __builtin_amdgcn_mfma_f32_16x16x32_bf16(av.s, bf01, c0, 0, 0, 0);
      c1 = __builtin_amdgcn_mfma_f32_16x16x32_bf16(av.s, bf11, c1, 0, 0, 0);
    }
#pragma unroll
    for (int r = 0; r < 4; ++r) {
      ms[(quad * 4 + r) * 44 + el] = c0[r] + b2a;
      ms[(quad * 4 + r) * 44 + 16 + el] = c1[r] + b2b;
    }
    wave_sync();
    if (have_next) {
#pragma unroll
      for (int t = 0; t < 4; ++t) {
        int r = __shfl(row_n, (t << 2) + xsub);
        glds16(xgb + (size_t)r * 128 + xcol, &xs[cur ^ 1][t * 512]);
      }
    }
    if (lane < 32) {
      int hi = quad;
      const float* mr = ms + el * 44 + hi * 16;
      float mloc[16];
#pragma unroll
      for (int i = 0; i < 4; ++i)
        *(float4*)(mloc + 4 * i) = *(const float4*)(mr + 4 * i);
      float F[16];
      so4_expm(mloc, F);
      float fu[16];
#pragma unroll
      for (int i = 0; i < 16; ++i) fu[i] = __shfl(F[i], el);
      float res[16];
#pragma unroll
      for (int aa = 0; aa < 4; ++aa)
#pragma unroll
        for (int bb = 0; bb < 4; ++bb) {
          float s = 0.f;
#pragma unroll
          for (int cc = 0; cc < 4; ++cc)
            s = fmaf(fu[cc * 4 + aa], F[cc * 4 + bb], s);
          res[aa * 4 + bb] = s;
        }
      if (hi == 0) {
        float* mw = ms + el * 44;
#pragma unroll
        for (int i = 0; i < 4; ++i)
          *(float4*)(mw + 4 * i) = *(const float4*)(res + 4 * i);
      } else {
        unsigned* mw32 = (unsigned*)(ms + el * 44 + 16);
#pragma unroll
        for (int w = 0; w < 8; ++w) {
          float lo = -res[2 * w], hi2 = -res[2 * w + 1];
          unsigned r;
          asm("v_cvt_pk_bf16_f32 %0, %1, %2" : "=v"(r) : "v"(lo), "v"(hi2));
          mw32[w] = r;
        }
      }
    }
    wave_sync();
    if (have_next) {
      asm volatile("s_waitcnt vmcnt(4)" ::: "memory");
    } else {
      asm volatile("s_waitcnt vmcnt(0)" ::: "memory");
    }
    __builtin_amdgcn_sched_barrier(0);
    const u16* xc = xs[cur];
    int j = 0;
    for (; j + 1 < nb; j += 2) {
      float4 am1 = *(const float4*)(ms + j * 44 + a * 4);
      float4 bm1 = *(const float4*)(ms + (j + 1) * 44 + a * 4);
      uint2 am2 = *(const uint2*)((const unsigned*)(ms + j * 44 + 16) + a * 2);
      uint2 bm2 =
          *(const uint2*)((const unsigned*)(ms + (j + 1) * 44 + 16) + a * 2);
      uint2 ua1 = *(const uint2*)(xc + j * 128 + kb);
      uint2 ua2 = *(const uint2*)(xc + j * 128 + 64 + kb);
      uint2 ub1 = *(const uint2*)(xc + (j + 1) * 128 + kb);
      uint2 ub2 = *(const uint2*)(xc + (j + 1) * 128 + 64 + kb);
      s10 += am1.x + bm1.x;
      s11 += am1.y + bm1.y;
      s12 += am1.z + bm1.z;
      s13 += am1.w + bm1.w;
      dot2bf(acc1, am2.x, ua1.x);
      dot2bf(acc1, am2.y, ua1.y);
      dot2bf(acc2, am2.x, ua2.x);
      dot2bf(acc2, am2.y, ua2.y);
      dot2bf(acc1, bm2.x, ub1.x);
      dot2bf(acc1, bm2.y, ub1.y);
      dot2bf(acc2, bm2.x, ub2.x);
      dot2bf(acc2, bm2.y, ub2.y);
    }
    if (j < nb) {
      float4 am1 = *(const float4*)(ms + j * 44 + a * 4);
      uint2 am2 = *(const uint2*)((const unsigned*)(ms + j * 44 + 16) + a * 2);
      uint2 ua1 = *(const uint2*)(xc + j * 128 + kb);
      uint2 ua2 = *(const uint2*)(xc + j * 128 + 64 + kb);
      s10 += am1.x;
      s11 += am1.y;
      s12 += am1.z;
      s13 += am1.w;
      dot2bf(acc1, am2.x, ua1.x);
      dot2bf(acc1, am2.y, ua1.y);
      dot2bf(acc2, am2.x, ua2.x);
      dot2bf(acc2, am2.y, ua2.y);
    }
    wave_sync();
    row = row_n;
    cur ^= 1;
  }
  float4 xi1 =
      make_float4(bf2f(xu1.x), bf2f(xu1.y), bf2f(xu1.z), bf2f(xu1.w));
  float4 xi2 =
      make_float4(bf2f(xu2.x), bf2f(xu2.y), bf2f(xu2.z), bf2f(xu2.w));
  float hv1 = (a == 0) ? xi1.x : (a == 1) ? xi1.y : (a == 2) ? xi1.z : xi1.w;
  float hv2 = (a == 0) ? xi2.x : (a == 1) ? xi2.y : (a == 2) ? xi2.z : xi2.w;
  acc1 += s10 * xi1.x + s11 * xi1.y + s12 * xi1.z + s13 * xi1.w;
  acc2 += s10 * xi2.x + s11 * xi2.y + s12 * xi2.z + s13 * xi2.w;
  float eps = *epsp;
  float r1 = hv1 - eps * acc1;
  float r2 = hv2 - eps * acc2;
  r1 = (r1 > 0.f) ? r1 : expm1f(r1);
  r2 = (r2 > 0.f) ? r2 : expm1f(r2);
  xoutb[(size_t)v * 128 + lane] = f2bf(r1);
  xoutb[(size_t)v * 128 + 64 + lane] = f2bf(r2);
}

// ---- fused conv (layer 1 clone): identical loop + fused out epilogue -------
__global__ void __launch_bounds__(64) k_conv_out(
    const u16* __restrict__ xgb, const u16* __restrict__ pb,
    const u16* __restrict__ qb,
    const u16* __restrict__ W2T, const float* __restrict__ b2,
    const int* __restrict__ deg, const u16* __restrict__ bucket,
    const float* __restrict__ epsp,
    const u16* __restrict__ wtout, const float* __restrict__ outb,
    float* __restrict__ outf, int N) {
  __shared__ float ms[16 * 44];
  __shared__ u16 xs[2][16 * 128];
  int lane = threadIdx.x;
  int v = blockIdx.x;
  if (v >= N) return;
  int el = lane & 15, quad = lane >> 4;
  int row = (int)bucket[(size_t)v * 64 + el];
  int dg = deg[v];
  if (dg > 64) dg = 64;
  int a = lane & 3, kb = lane & ~3;
  int xsub = lane >> 4;
  int xcol = (lane & 15) * 8;
  short8 bf00 = *(const short8*)(W2T + (size_t)el * 64 + quad * 8);
  short8 bf01 = *(const short8*)(W2T + (size_t)el * 64 + 32 + quad * 8);
  short8 bf10 = *(const short8*)(W2T + (size_t)(16 + el) * 64 + quad * 8);
  short8 bf11 = *(const short8*)(W2T + (size_t)(16 + el) * 64 + 32 + quad * 8);
  float b2a = b2[el], b2b = b2[16 + el];
  short8 qv0 = *(const short8*)(qb + (size_t)v * 64 + quad * 8);
  short8 qv1 = *(const short8*)(qb + (size_t)v * 64 + 32 + quad * 8);
  ushort4 xu1 = *(const ushort4*)(xgb + (size_t)v * 128 + kb);
  ushort4 xu2 = *(const ushort4*)(xgb + (size_t)v * 128 + 64 + kb);
  float s10 = 0.f, s11 = 0.f, s12 = 0.f, s13 = 0.f;
  float acc1 = 0.f, acc2 = 0.f;
  int cur = 0;
  if (dg > 0) {
#pragma unroll
    for (int t = 0; t < 4; ++t) {
      int r = __shfl(row, (t << 2) + xsub);
      glds16(xgb + (size_t)r * 128 + xcol, &xs[0][t * 512]);
    }
  }
  for (int b0 = 0; b0 < dg; b0 += 16) {
    int nb = dg - b0;
    nb = (nb > 16) ? 16 : nb;
    int have_next = (b0 + 16 < dg);
    int row_n = row;
    if (have_next) {
      int nb2 = dg - b0 - 16;
      nb2 = (nb2 > 16) ? 16 : nb2;
      int ee2 = b0 + 16 + ((el < nb2) ? el : (nb2 - 1));
      row_n = (int)bucket[(size_t)v * 64 + ee2];
    }
    f32x4 c0 = {0.f, 0.f, 0.f, 0.f};
    f32x4 c1 = {0.f, 0.f, 0.f, 0.f};
    {
      short8 pv = *(const short8*)(pb + (size_t)row * 64 + quad * 8);
      union { short8 s; unsigned u[4]; } av;
#pragma unroll
      for (int j2 = 0; j2 < 4; ++j2) {
        float h0 = fmaxf(bf2f((u16)pv[2 * j2]) + bf2f((u16)qv0[2 * j2]), 0.f);
        float h1 = fmaxf(
            bf2f((u16)pv[2 * j2 + 1]) + bf2f((u16)qv0[2 * j2 + 1]), 0.f);
        unsigned r;
        asm("v_cvt_pk_bf16_f32 %0, %1, %2" : "=v"(r) : "v"(h0), "v"(h1));
        av.u[j2] = r;
      }
      c0 = __builtin_amdgcn_mfma_f32_16x16x32_bf16(av.s, bf00, c0, 0, 0, 0);
      c1 = __builtin_amdgcn_mfma_f32_16x16x32_bf16(av.s, bf10, c1, 0, 0, 0);
    }
    {
      short8 pv = *(const short8*)(pb + (size_t)row * 64 + 32 + quad * 8);
      union { short8 s; unsigned u[4]; } av;
#pragma unroll
      for (int j2 = 0; j2 < 4; ++j2) {
        float h0 = fmaxf(bf2f((u16)pv[2 * j2]) + bf2f((u16)qv1[2 * j2]), 0.f);
        float h1 = fmaxf(
            bf2f((u16)pv[2 * j2 + 1]) + bf2f((u16)qv1[2 * j2 + 1]), 0.f);
        unsigned r;
        asm("v_cvt_pk_bf16_f32 %0, %1, %2" : "=v"(r) : "v"(h0), "v"(h1));
        av.u[j2] = r;
      }
      c0 = __builtin_amdgcn_mfma_f32_16x16x32_bf16(av.s, bf01, c0, 0, 0, 0);
      c1 = __builtin_amdgcn_mfma_f32_16x16x32_bf16(av.s, bf11, c1, 0, 0, 0);
    }
#pragma unroll
    for (int r = 0; r < 4; ++r) {
      ms[(quad * 4 + r) * 44 + el] = c0[r] + b2a;
      ms[(quad * 4 + r) * 44 + 16 + el] = c1[r] + b2b;
    }
    wave_sync();
    if (have_next) {
#pragma unroll
      for (int t = 0; t < 4; ++t) {
        int r = __shfl(row_n, (t << 2) + xsub);
        glds16(xgb + (size_t)r * 128 + xcol, &xs[cur ^ 1][t * 512]);
      }
    }
    if (lane < 32) {
      int hi = quad;
      const float* mr = ms + el * 44 + hi * 16;
      float mloc[16];
#pragma unroll
      for (int i = 0; i < 4; ++i)
        *(float4*)(mloc + 4 * i) = *(const float4*)(mr + 4 * i);
      float F[16];
      so4_expm(mloc, F);
      float fu[16];
#pragma unroll
      for (int i = 0; i < 16; ++i) fu[i] = __shfl(F[i], el);
      float res[16];
#pragma unroll
      for (int aa = 0; aa < 4; ++aa)
#pragma unroll
        for (int bb = 0; bb < 4; ++bb) {
          float s = 0.f;
#pragma unroll
          for (int cc = 0; cc < 4; ++cc)
            s = fmaf(fu[cc * 4 + aa], F[cc * 4 + bb], s);
          res[aa * 4 + bb] = s;
        }
      if (hi == 0) {
        float* mw = ms + el * 44;
#pragma unroll
        for (int i = 0; i < 4; ++i)
          *(float4*)(mw + 4 * i) = *(const float4*)(res + 4 * i);
      } else {
        unsigned* mw32 = (unsigned*)(ms + el * 44 + 16);
#pragma unroll
        for (int w = 0; w < 8; ++w) {
          float lo = -res[2 * w], hi2 = -res[2 * w + 1];
          unsigned r;
          asm("v_cvt_pk_bf16_f32 %0, %1, %2" : "=v"(r) : "v"(lo), "v"(hi2));
          mw32[w] = r;
        }
      }
    }
    wave_sync();
    if (have_next) {
      asm volatile("s_waitcnt vmcnt(4)" ::: "memory");
    } else {
      asm volatile("s_waitcnt vmcnt(0)" ::: "memory");
    }
    __builtin_amdgcn_sched_barrier(0);
    const u16* xc = xs[cur];
    int j = 0;
    for (; j + 1 < nb; j += 2) {
      float4 am1 = *(const float4*)(ms + j * 44 + a * 4);
      float4 bm1 = *(const float4*)(ms + (j + 1) * 44 + a * 4);
      uint2 am2 = *(const uint2*)((const unsigned*)(ms + j * 44 + 16) + a * 2);
      uint2 bm2 =
          *(const uint2*)((const unsigned*)(ms + (j + 1) * 44 + 16) + a * 2);
      uint2 ua1 = *(const uint2*)(xc + j * 128 + kb);
      uint2 ua2 = *(const uint2*)(xc + j * 128 + 64 + kb);
      uint2 ub1 = *(const uint2*)(xc + (j + 1) * 128 + kb);
      uint2 ub2 = *(const uint2*)(xc + (j + 1) * 128 + 64 + kb);
      s10 += am1.x + bm1.x;
      s11 += am1.y + bm1.y;
      s12 += am1.z + bm1.z;
      s13 += am1.w + bm1.w;
      dot2bf(acc1, am2.x, ua1.x);
      dot2bf(acc1, am2.y, ua1.y);
      dot2bf(acc2, am2.x, ua2.x);
      dot2bf(acc2, am2.y, ua2.y);
      dot2bf(acc1, bm2.x, ub1.x);
      dot2bf(acc1, bm2.y, ub1.y);
      dot2bf(acc2, bm2.x, ub2.x);
      dot2bf(acc2, bm2.y, ub2.y);
    }
    if (j < nb) {
      float4 am1 = *(const float4*)(ms + j * 44 + a * 4);
      uint2 am2 = *(const uint2*)((const unsigned*)(ms + j * 44 + 16) + a * 2);
      uint2 ua1 = *(const uint2*)(xc + j * 128 + kb);
      uint2 ua2 = *(const uint2*)(xc + j * 128 + 64 + kb);
      s10 += am1.x;
      s11 += am1.y;
      s12 += am1.z;
      s13 += am1.w;
      dot2bf(acc1, am2.x, ua1.x);
      dot2bf(acc1, am2.y, ua1.y);
      dot2bf(acc2, am2.x, ua2.x);
      dot2bf(acc2, am2.y, ua2.y);
    }
    wave_sync();
    row = row_n;
    cur ^= 1;
  }
  float4 xi1 =
      make_float4(bf2f(xu1.x), bf2f(xu1.y), bf2f(xu1.z), bf2f(xu1.w));
  float4 xi2 =
      make_float4(bf2f(xu2.x), bf2f(xu2.y), bf2f(xu2.z), bf2f(xu2.w));
  float hv1 = (a == 0) ? xi1.x : (a == 1) ? xi1.y : (a == 2) ? xi1.z : xi1.w;
  float hv2 = (a == 0) ? xi2.x : (a == 1) ? xi2.y : (a == 2) ? xi2.z : xi2.w;
  acc1 += s10 * xi1.x + s11 * xi1.y + s12 * xi1.z + s13 * xi1.w;
  acc2 += s10 * xi2.x + s11 * xi2.y + s12 * xi2.z + s13 * xi2.w;
  float eps = *epsp;
  float r1 = hv1 - eps * acc1;
  float r2 = hv2 - eps * acc2;
  r1 = (r1 > 0.f) ? r1 : expm1f(r1);
  r2 = (r2 > 0.f) ? r2 : expm1f(r2);
  // fused out = h @ Wout + b: pack h-row bf16 into (dead) ms LDS,
  // lane l dots against WTout row l (contiguous 128 u16, L2-hot).
  u16* hrow = (u16*)ms;
  hrow[lane] = f2bf(r1);
  hrow[64 + lane] = f2bf(r2);
  wave_sync();
  const unsigned* hr32 = (const unsigned*)hrow;
  const u16* wr = wtout + (size_t)lane * 128;
  float acc = outb[lane];
#pragma unroll
  for (int w = 0; w < 16; ++w) {
    short8 wv = *(const short8*)(wr + w * 8);
    union { short8 s; unsigned u[4]; } wu;
    wu.s = wv;
    dot2bf(acc, hr32[w * 4 + 0], wu.u[0]);
    dot2bf(acc, hr32[w * 4 + 1], wu.u[1]);
    dot2bf(acc, hr32[w * 4 + 2], wu.u[2]);
    dot2bf(acc, hr32[w * 4 + 3], wu.u[3]);
  }
  outf[(size_t)v * 64 + lane] = acc;
}

extern "C" void kernel_launch(void* const* d_in, const int* in_sizes, int n_in,
                              void* d_out, int out_size, void* d_ws,
                              size_t ws_size, hipStream_t stream) {
  const float* x = (const float*)d_in[0];
  const int* eidx = (const int*)d_in[1];
  const float* lin_in_w = (const float*)d_in[2];
  const float* lin_in_b = (const float*)d_in[3];
  const float* c0w1 = (const float*)d_in[4];
  const float* c0b1 = (const float*)d_in[5];
  const float* c0w2 = (const float*)d_in[6];
  const float* c0b2 = (const float*)d_in[7];
  const float* c0eps = (const float*)d_in[8];
  const float* c1w1 = (const float*)d_in[9];
  const float* c1b1 = (const float*)d_in[10];
  const float* c1w2 = (const float*)d_in[11];
  const float* c1b2 = (const float*)d_in[12];
  const float* c1eps = (const float*)d_in[13];
  const float* lout_w = (const float*)d_in[14];
  const float* lout_b = (const float*)d_in[15];
  float* out = (float*)d_out;

  int N = in_sizes[0] / 128;
  int E = in_sizes[1] / 2;
  int Npad = N + 64;

  char* ws = (char*)d_ws;
  size_t szHb = (size_t)Npad * 128 * 2;
  size_t szPb = (size_t)Npad * 64 * 2;
  u16* Xb = (u16*)ws;
  u16* Hb = (u16*)(ws + szHb);
  u16* H2b = (u16*)(ws + 2 * szHb);
  u16* Pb = (u16*)(ws + 3 * szHb);
  u16* Qb = (u16*)(ws + 3 * szHb + szPb);
  u16* WTin = (u16*)(ws + 3 * szHb + 2 * szPb);
  u16* WT1a = WTin + 16384;
  u16* WT1b = WT1a + 16384;
  u16* WTout = WT1b + 16384;
  u16* W2Ta = WTout + 8192;
  u16* W2Tb = W2Ta + 2048;
  float* B1pa = (float*)(W2Tb + 2048);
  float* B1pb = B1pa + 128;
  char* ip = (char*)(B1pb + 128);
  int* cnt = (int*)ip;                                  // N
  u16* bucket = (u16*)(ip + 4 * (size_t)(N + 64));      // N*64 u16

  dim3 blk(256);
  int gN = (N + 63) / 64;
  int gE = (E + 255) / 256;

  // fused prep
  k_prep<<<(N * 32 + 255) / 256, blk, 0, stream>>>(
      x, Xb, cnt, N * 32, N, lin_in_w, c0w1, c1w1, lout_w, c0w2, c1w2, c0b1,
      c1b1, WTin, WT1a, WT1b, WTout, W2Ta, W2Tb, B1pa, B1pb,
      (unsigned*)bucket);

  // MERGED: h0 GEMM (2*gN blocks) + bucket fill (gE blocks)
  k_h0_fill<<<2 * gN + gE, blk, 0, stream>>>(Xb, WTin, lin_in_b, Hb, N, gN,
                                             eidx, cnt, bucket, E);

  // layer 0
  k_gemm_mfma<<<dim3(gN, 2), blk, 0, stream>>>(Hb, WT1a, B1pa, Pb, Qb, N,
                                               128);
  k_conv<<<N, dim3(64), 0, stream>>>(Hb, Pb, Qb, W2Ta, c0b2, cnt, bucket,
                                     c0eps, H2b, N);

  // layer 1 (out-GEMM fused into the conv-clone epilogue)
  k_gemm_mfma<<<dim3(gN, 2), blk, 0, stream>>>(H2b, WT1b, B1pb, Pb, Qb, N,
                                               128);
  k_conv_out<<<N, dim3(64), 0, stream>>>(H2b, Pb, Qb, W2Tb, c1b2, cnt, bucket,
                                         c1eps, WTout, lout_b, out, N);
}

// Round 23
// 228.387 us; speedup vs baseline: 1.0712x; 1.0660x over previous
//
#include <hip/hip_runtime.h>
#include <math.h>

// ---------------------------------------------------------------------------
// SheafGNN forward. R35 = R32 VERBATIM (best: 227.1us).
// R33/R34 lesson (pre-registered revert): fusing out=h@Wout+b into the conv
// epilogue is structurally bad -- the u16-aliased store into float ms[]
// kills the loop's alias independence (VALUBusy 46->33, conv 45->71us),
// and the per-block 16KB WTout read adds ~320MB L2 traffic. Keep the
// separate out-GEMM dispatch.
// Pinned: bucket CSR (R30); Pb/Qb split (R31); h0+fill merge (R32);
// 1-wave WGs; xs dbuf + counted vmcnt; lgkm fences; 32-lane expm spread;
// dot2 aggregation; A-reuse GEMM (gN,2); bf16-only activations; VGPR 68.
// ---------------------------------------------------------------------------

using short8 = __attribute__((ext_vector_type(8))) short;
using f32x4 = __attribute__((ext_vector_type(4))) float;
typedef unsigned short u16;

__device__ __forceinline__ u16 f2bf(float f) {  // RNE fp32->bf16
  unsigned u = __float_as_uint(f);
  unsigned r = (u + 0x7FFFu + ((u >> 16) & 1u)) >> 16;
  return (u16)r;
}
__device__ __forceinline__ float bf2f(u16 v) {
  return __uint_as_float(((unsigned)v) << 16);
}

// per-wave LDS fence (1-wave block): orders ds_write -> ds_read without
// draining vmcnt (keeps global_load_lds prefetches in flight).
__device__ __forceinline__ void wave_sync() {
  __builtin_amdgcn_sched_barrier(0);
  asm volatile("s_waitcnt lgkmcnt(0)" ::: "memory");
  __builtin_amdgcn_sched_barrier(0);
}

// async 16B/lane global->LDS: HW dest = lds_base + lane*16 (wave-uniform
// base); global src is per-lane. Tracked by vmcnt.
__device__ __forceinline__ void glds16(const void* g, void* l) {
  __builtin_amdgcn_global_load_lds(
      (const __attribute__((address_space(1))) unsigned int*)g,
      (__attribute__((address_space(3))) unsigned int*)l, 16, 0, 0);
}

// packed bf16 dot2-accumulate: acc += a.lo*b.lo + a.hi*b.hi (fp32 accum)
__device__ __forceinline__ void dot2bf(float& acc, unsigned a, unsigned b) {
  asm("v_dot2_f32_bf16 %0, %1, %2, %0" : "+v"(acc) : "v"(a), "v"(b));
}

// ---- fused one-time prep: x->bf16, cnt/bucket zero, weight packs, bias -----
__global__ void __launch_bounds__(256) k_prep(const float* __restrict__ x,
    u16* __restrict__ Xb, int* __restrict__ cnt, int n4, int N,
    const float* __restrict__ win, const float* __restrict__ w1a,
    const float* __restrict__ w1b, const float* __restrict__ wout,
    const float* __restrict__ w2a, const float* __restrict__ w2b,
    const float* __restrict__ b1a, const float* __restrict__ b1b,
    u16* __restrict__ WTin, u16* __restrict__ WT1a, u16* __restrict__ WT1b,
    u16* __restrict__ WTout, u16* __restrict__ W2Ta, u16* __restrict__ W2Tb,
    float* __restrict__ B1pa, float* __restrict__ B1pb,
    unsigned* __restrict__ bucket32) {
  int idx = blockIdx.x * 256 + threadIdx.x;
  if (idx < N) cnt[idx] = 0;
  if (idx < N * 32) bucket32[idx] = 0;  // pad rows -> node 0 (valid, unused)
  if (idx < n4) {
    float4 v = ((const float4*)x)[idx];
    ushort4 o;
    o.x = f2bf(v.x);
    o.y = f2bf(v.y);
    o.z = f2bf(v.z);
    o.w = f2bf(v.w);
    ((ushort4*)Xb)[idx] = o;
  }
  if (idx < 16384) {
    int o = idx >> 7, i = idx & 127;
    WTin[idx] = f2bf(win[i * 128 + o]);
  } else if (idx < 32768) {
    int j = idx - 16384;
    int o = j >> 7, i = j & 127;
    WT1a[j] = f2bf(o < 64 ? w1a[i * 64 + o] : w1a[(128 + i) * 64 + (o - 64)]);
  } else if (idx < 49152) {
    int j = idx - 32768;
    int o = j >> 7, i = j & 127;
    WT1b[j] = f2bf(o < 64 ? w1b[i * 64 + o] : w1b[(128 + i) * 64 + (o - 64)]);
  } else if (idx < 57344) {
    int j = idx - 49152;
    int o = j >> 7, i = j & 127;  // o < 64
    WTout[j] = f2bf(wout[i * 64 + o]);
  } else if (idx < 59392) {
    int j = idx - 57344;
    int o = j >> 6, k = j & 63;  // W2T[o][k] = w2[k][o]
    W2Ta[j] = f2bf(w2a[k * 32 + o]);
  } else if (idx < 61440) {
    int j = idx - 59392;
    int o = j >> 6, k = j & 63;
    W2Tb[j] = f2bf(w2b[k * 32 + o]);
  } else if (idx < 61568) {
    int j = idx - 61440;
    B1pa[j] = (j < 64) ? 0.f : b1a[j - 64];
  } else if (idx < 61696) {
    int j = idx - 61568;
    B1pb[j] = (j < 64) ? 0.f : b1b[j - 64];
  }
}

// ---- bf16 MFMA GEMM: wave = 16 rows, loops P/32 col-tiles ------------------
// Split-epilogue mode (Cb2 != null): col<64 -> Cb, col>=64 -> Cb2 (stride 64).
// C != null: fp32 output (stride P).
__global__ void __launch_bounds__(256) k_gemm_mfma(const u16* __restrict__ Ab,
    const u16* __restrict__ WT, const float* __restrict__ bias,
    float* __restrict__ C, u16* __restrict__ Cb, u16* __restrict__ Cb2,
    int N, int P) {
  int t = threadIdx.x;
  int wv = t >> 6, lane = t & 63;
  int row0 = (blockIdx.x << 6) + (wv << 4);
  int col = lane & 15, quad = lane >> 4;
  const u16* ar = Ab + (size_t)(row0 + col) * 128 + quad * 8;
  short8 a0 = *(const short8*)(ar);
  short8 a1 = *(const short8*)(ar + 32);
  short8 a2 = *(const short8*)(ar + 64);
  short8 a3 = *(const short8*)(ar + 96);
  int tiles = P >> 5;
  int ct0 = blockIdx.y * tiles;
  for (int ct = 0; ct < tiles; ++ct) {
    int cb = (ct0 + ct) << 4;
    const u16* wrow = WT + (size_t)(cb + col) * 128 + quad * 8;
    short8 b0 = *(const short8*)(wrow);
    short8 b1 = *(const short8*)(wrow + 32);
    short8 b2 = *(const short8*)(wrow + 64);
    short8 b3 = *(const short8*)(wrow + 96);
    float bv = bias ? bias[cb + col] : 0.f;
    f32x4 acc = {0.f, 0.f, 0.f, 0.f};
    acc = __builtin_amdgcn_mfma_f32_16x16x32_bf16(a0, b0, acc, 0, 0, 0);
    acc = __builtin_amdgcn_mfma_f32_16x16x32_bf16(a1, b1, acc, 0, 0, 0);
    acc = __builtin_amdgcn_mfma_f32_16x16x32_bf16(a2, b2, acc, 0, 0, 0);
    acc = __builtin_amdgcn_mfma_f32_16x16x32_bf16(a3, b3, acc, 0, 0, 0);
#pragma unroll
    for (int r = 0; r < 4; ++r) {
      int row = row0 + quad * 4 + r;
      if (row < N) {
        float o = acc[r] + bv;
        if (C) C[(size_t)row * P + cb + col] = o;
        if (Cb) {
          int cc = cb + col;
          if (!Cb2) {
            Cb[(size_t)row * 128 + cc] = f2bf(o);
          } else if (cc < 64) {
            Cb[(size_t)row * 64 + cc] = f2bf(o);
          } else {
            Cb2[(size_t)row * 64 + (cc - 64)] = f2bf(o);
          }
        }
      }
    }
  }
}

// ---- MERGED: h0-GEMM (blocks [0,2gN)) + bucket fill (blocks >= 2gN) --------
__global__ void __launch_bounds__(256) k_h0_fill(const u16* __restrict__ Ab,
    const u16* __restrict__ WT, const float* __restrict__ bias,
    u16* __restrict__ Cb, int N, int gN,
    const int* __restrict__ eidx, int* __restrict__ cnt,
    u16* __restrict__ bucket, int E) {
  int b = blockIdx.x;
  if (b < 2 * gN) {
    int t = threadIdx.x;
    int wv = t >> 6, lane = t & 63;
    int bx = (b < gN) ? b : (b - gN);
    int by = (b < gN) ? 0 : 1;
    int row0 = (bx << 6) + (wv << 4);
    int col = lane & 15, quad = lane >> 4;
    const u16* ar = Ab + (size_t)(row0 + col) * 128 + quad * 8;
    short8 a0 = *(const short8*)(ar);
    short8 a1 = *(const short8*)(ar + 32);
    short8 a2 = *(const short8*)(ar + 64);
    short8 a3 = *(const short8*)(ar + 96);
    int ct0 = by * 4;
    for (int ct = 0; ct < 4; ++ct) {
      int cb = (ct0 + ct) << 4;
      const u16* wrow = WT + (size_t)(cb + col) * 128 + quad * 8;
      short8 b0 = *(const short8*)(wrow);
      short8 b1 = *(const short8*)(wrow + 32);
      short8 b2 = *(const short8*)(wrow + 64);
      short8 b3 = *(const short8*)(wrow + 96);
      float bv = bias[cb + col];
      f32x4 acc = {0.f, 0.f, 0.f, 0.f};
      acc = __builtin_amdgcn_mfma_f32_16x16x32_bf16(a0, b0, acc, 0, 0, 0);
      acc = __builtin_amdgcn_mfma_f32_16x16x32_bf16(a1, b1, acc, 0, 0, 0);
      acc = __builtin_amdgcn_mfma_f32_16x16x32_bf16(a2, b2, acc, 0, 0, 0);
      acc = __builtin_amdgcn_mfma_f32_16x16x32_bf16(a3, b3, acc, 0, 0, 0);
#pragma unroll
      for (int r = 0; r < 4; ++r) {
        int row = row0 + quad * 4 + r;
        if (row < N) {
          Cb[(size_t)row * 128 + cb + col] = f2bf(acc[r] + bv);
        }
      }
    }
  } else {
    int e = (b - 2 * gN) * 256 + threadIdx.x;
    if (e >= E) return;
    int r = eidx[e], c = eidx[E + e];
    int pos = atomicAdd(&cnt[c], 1);
    if (pos < 64) bucket[(size_t)c * 64 + pos] = (u16)r;
  }
}

// ---- exact expm of antisym 4x4 via so(4) = su(2) + su(2) -------------------
__device__ __forceinline__ void so4_expm(const float* __restrict__ m,
                                         float* __restrict__ F) {
  float v1 = m[1] - m[4], v2 = m[2] - m[8], v3 = m[3] - m[12];
  float w1 = m[11] - m[14], w2 = m[13] - m[7], w3 = m[6] - m[9];
  float p1 = 0.5f * (v1 + w1), p2 = 0.5f * (v2 + w2), p3 = 0.5f * (v3 + w3);
  float q1 = 0.5f * (v1 - w1), q2 = 0.5f * (v2 - w2), q3 = 0.5f * (v3 - w3);
  float tp2 = p1 * p1 + p2 * p2 + p3 * p3;
  float tq2 = q1 * q1 + q2 * q2 + q3 * q3;
  float tp = sqrtf(tp2), tq = sqrtf(tq2);
  float cp = __cosf(tp);
  float sp = (tp > 1e-6f) ? (__sinf(tp) / tp) : (1.f - tp2 * (1.f / 6.f));
  float cq = __cosf(tq);
  float sq = (tq > 1e-6f) ? (__sinf(tq) / tq) : (1.f - tq2 * (1.f / 6.f));
  float a1 = sp * p1, a2 = sp * p2, a3 = sp * p3;
  float b1 = sq * q1, b2 = sq * q2, b3 = sq * q3;
  float Rp[16] = {cp,  a1,  a2,  a3,  -a1, cp,  a3,  -a2,
                  -a2, -a3, cp,  a1,  -a3, a2,  -a1, cp};
  float Rq[16] = {cq,  b1,  b2,  b3,  -b1, cq,  -b3, b2,
                  -b2, b3,  cq,  -b1, -b3, -b2, b1,  cq};
#pragma unroll
  for (int a = 0; a < 4; ++a)
#pragma unroll
    for (int b = 0; b < 4; ++b) {
      float s = 0.f;
#pragma unroll
      for (int c = 0; c < 4; ++c) s = fmaf(Rp[a * 4 + c], Rq[c * 4 + b], s);
      F[a * 4 + b] = s;
    }
}

// ---- fused conv: one node per single-wave block, bucket entry + prefetch ---
__global__ void __launch_bounds__(64) k_conv(
    const u16* __restrict__ xgb, const u16* __restrict__ pb,
    const u16* __restrict__ qb,
    const u16* __restrict__ W2T, const float* __restrict__ b2,
    const int* __restrict__ deg, const u16* __restrict__ bucket,
    const float* __restrict__ epsp,
    u16* __restrict__ xoutb, int N) {
  __shared__ float ms[16 * 44];
  __shared__ u16 xs[2][16 * 128];  // staged xgb rows, double-buffered
  int lane = threadIdx.x;
  int v = blockIdx.x;
  if (v >= N) return;
  int el = lane & 15, quad = lane >> 4;
  int row = (int)bucket[(size_t)v * 64 + el];
  int dg = deg[v];
  if (dg > 64) dg = 64;
  int a = lane & 3, kb = lane & ~3;
  int xsub = lane >> 4;
  int xcol = (lane & 15) * 8;
  short8 bf00 = *(const short8*)(W2T + (size_t)el * 64 + quad * 8);
  short8 bf01 = *(const short8*)(W2T + (size_t)el * 64 + 32 + quad * 8);
  short8 bf10 = *(const short8*)(W2T + (size_t)(16 + el) * 64 + quad * 8);
  short8 bf11 = *(const short8*)(W2T + (size_t)(16 + el) * 64 + 32 + quad * 8);
  float b2a = b2[el], b2b = b2[16 + el];
  short8 qv0 = *(const short8*)(qb + (size_t)v * 64 + quad * 8);
  short8 qv1 = *(const short8*)(qb + (size_t)v * 64 + 32 + quad * 8);
  ushort4 xu1 = *(const ushort4*)(xgb + (size_t)v * 128 + kb);
  ushort4 xu2 = *(const ushort4*)(xgb + (size_t)v * 128 + 64 + kb);
  float s10 = 0.f, s11 = 0.f, s12 = 0.f, s13 = 0.f;
  float acc1 = 0.f, acc2 = 0.f;
  int cur = 0;
  if (dg > 0) {
#pragma unroll
    for (int t = 0; t < 4; ++t) {
      int r = __shfl(row, (t << 2) + xsub);
      glds16(xgb + (size_t)r * 128 + xcol, &xs[0][t * 512]);
    }
  }
  for (int b0 = 0; b0 < dg; b0 += 16) {
    int nb = dg - b0;
    nb = (nb > 16) ? 16 : nb;
    int have_next = (b0 + 16 < dg);
    int row_n = row;
    if (have_next) {
      int nb2 = dg - b0 - 16;
      nb2 = (nb2 > 16) ? 16 : nb2;
      int ee2 = b0 + 16 + ((el < nb2) ? el : (nb2 - 1));
      row_n = (int)bucket[(size_t)v * 64 + ee2];
    }
    f32x4 c0 = {0.f, 0.f, 0.f, 0.f};
    f32x4 c1 = {0.f, 0.f, 0.f, 0.f};
    {
      short8 pv = *(const short8*)(pb + (size_t)row * 64 + quad * 8);
      union { short8 s; unsigned u[4]; } av;
#pragma unroll
      for (int j2 = 0; j2 < 4; ++j2) {
        float h0 = fmaxf(bf2f((u16)pv[2 * j2]) + bf2f((u16)qv0[2 * j2]), 0.f);
        float h1 = fmaxf(
            bf2f((u16)pv[2 * j2 + 1]) + bf2f((u16)qv0[2 * j2 + 1]), 0.f);
        unsigned r;
        asm("v_cvt_pk_bf16_f32 %0, %1, %2" : "=v"(r) : "v"(h0), "v"(h1));
        av.u[j2] = r;
      }
      c0 = __builtin_amdgcn_mfma_f32_16x16x32_bf16(av.s, bf00, c0, 0, 0, 0);
      c1 = __builtin_amdgcn_mfma_f32_16x16x32_bf16(av.s, bf10, c1, 0, 0, 0);
    }
    {
      short8 pv = *(const short8*)(pb + (size_t)row * 64 + 32 + quad * 8);
      union { short8 s; unsigned u[4]; } av;
#pragma unroll
      for (int j2 = 0; j2 < 4; ++j2) {
        float h0 = fmaxf(bf2f((u16)pv[2 * j2]) + bf2f((u16)qv1[2 * j2]), 0.f);
        float h1 = fmaxf(
            bf2f((u16)pv[2 * j2 + 1]) + bf2f((u16)qv1[2 * j2 + 1]), 0.f);
        unsigned r;
        asm("v_cvt_pk_bf16_f32 %0, %1, %2" : "=v"(r) : "v"(h0), "v"(h1));
        av.u[j2] = r;
      }
      c0 = __builtin_amdgcn_mfma_f32_16x16x32_bf16(av.s, bf01, c0, 0, 0, 0);
      c1 = __builtin_amdgcn_mfma_f32_16x16x32_bf16(av.s, bf11, c1, 0, 0, 0);
    }
#pragma unroll
    for (int r = 0; r < 4; ++r) {
      ms[(quad * 4 + r) * 44 + el] = c0[r] + b2a;
      ms[(quad * 4 + r) * 44 + 16 + el] = c1[r] + b2b;
    }
    wave_sync();
    if (have_next) {
#pragma unroll
      for (int t = 0; t < 4; ++t) {
        int r = __shfl(row_n, (t << 2) + xsub);
        glds16(xgb + (size_t)r * 128 + xcol, &xs[cur ^ 1][t * 512]);
      }
    }
    if (lane < 32) {
      int hi = quad;
      const float* mr = ms + el * 44 + hi * 16;
      float mloc[16];
#pragma unroll
      for (int i = 0; i < 4; ++i)
        *(float4*)(mloc + 4 * i) = *(const float4*)(mr + 4 * i);
      float F[16];
      so4_expm(mloc, F);
      float fu[16];
#pragma unroll
      for (int i = 0; i < 16; ++i) fu[i] = __shfl(F[i], el);
      float res[16];
#pragma unroll
      for (int aa = 0; aa < 4; ++aa)
#pragma unroll
        for (int bb = 0; bb < 4; ++bb) {
          float s = 0.f;
#pragma unroll
          for (int cc = 0; cc < 4; ++cc)
            s = fmaf(fu[cc * 4 + aa], F[cc * 4 + bb], s);
          res[aa * 4 + bb] = s;
        }
      if (hi == 0) {
        float* mw = ms + el * 44;
#pragma unroll
        for (int i = 0; i < 4; ++i)
          *(float4*)(mw + 4 * i) = *(const float4*)(res + 4 * i);
      } else {
        unsigned* mw32 = (unsigned*)(ms + el * 44 + 16);
#pragma unroll
        for (int w = 0; w < 8; ++w) {
          float lo = -res[2 * w], hi2 = -res[2 * w + 1];
          unsigned r;
          asm("v_cvt_pk_bf16_f32 %0, %1, %2" : "=v"(r) : "v"(lo), "v"(hi2));
          mw32[w] = r;
        }
      }
    }
    wave_sync();
    if (have_next) {
      asm volatile("s_waitcnt vmcnt(4)" ::: "memory");
    } else {
      asm volatile("s_waitcnt vmcnt(0)" ::: "memory");
    }
    __builtin_amdgcn_sched_barrier(0);
    const u16* xc = xs[cur];
    int j = 0;
    for (; j + 1 < nb; j += 2) {
      float4 am1 = *(const float4*)(ms + j * 44 + a * 4);
      float4 bm1 = *(const float4*)(ms + (j + 1) * 44 + a * 4);
      uint2 am2 = *(const uint2*)((const unsigned*)(ms + j * 44 + 16) + a * 2);
      uint2 bm2 =
          *(const uint2*)((const unsigned*)(ms + (j + 1) * 44 + 16) + a * 2);
      uint2 ua1 = *(const uint2*)(xc + j * 128 + kb);
      uint2 ua2 = *(const uint2*)(xc + j * 128 + 64 + kb);
      uint2 ub1 = *(const uint2*)(xc + (j + 1) * 128 + kb);
      uint2 ub2 = *(const uint2*)(xc + (j + 1) * 128 + 64 + kb);
      s10 += am1.x + bm1.x;
      s11 += am1.y + bm1.y;
      s12 += am1.z + bm1.z;
      s13 += am1.w + bm1.w;
      dot2bf(acc1, am2.x, ua1.x);
      dot2bf(acc1, am2.y, ua1.y);
      dot2bf(acc2, am2.x, ua2.x);
      dot2bf(acc2, am2.y, ua2.y);
      dot2bf(acc1, bm2.x, ub1.x);
      dot2bf(acc1, bm2.y, ub1.y);
      dot2bf(acc2, bm2.x, ub2.x);
      dot2bf(acc2, bm2.y, ub2.y);
    }
    if (j < nb) {
      float4 am1 = *(const float4*)(ms + j * 44 + a * 4);
      uint2 am2 = *(const uint2*)((const unsigned*)(ms + j * 44 + 16) + a * 2);
      uint2 ua1 = *(const uint2*)(xc + j * 128 + kb);
      uint2 ua2 = *(const uint2*)(xc + j * 128 + 64 + kb);
      s10 += am1.x;
      s11 += am1.y;
      s12 += am1.z;
      s13 += am1.w;
      dot2bf(acc1, am2.x, ua1.x);
      dot2bf(acc1, am2.y, ua1.y);
      dot2bf(acc2, am2.x, ua2.x);
      dot2bf(acc2, am2.y, ua2.y);
    }
    wave_sync();
    row = row_n;
    cur ^= 1;
  }
  float4 xi1 =
      make_float4(bf2f(xu1.x), bf2f(xu1.y), bf2f(xu1.z), bf2f(xu1.w));
  float4 xi2 =
      make_float4(bf2f(xu2.x), bf2f(xu2.y), bf2f(xu2.z), bf2f(xu2.w));
  float hv1 = (a == 0) ? xi1.x : (a == 1) ? xi1.y : (a == 2) ? xi1.z : xi1.w;
  float hv2 = (a == 0) ? xi2.x : (a == 1) ? xi2.y : (a == 2) ? xi2.z : xi2.w;
  acc1 += s10 * xi1.x + s11 * xi1.y + s12 * xi1.z + s13 * xi1.w;
  acc2 += s10 * xi2.x + s11 * xi2.y + s12 * xi2.z + s13 * xi2.w;
  float eps = *epsp;
  float r1 = hv1 - eps * acc1;
  float r2 = hv2 - eps * acc2;
  r1 = (r1 > 0.f) ? r1 : expm1f(r1);
  r2 = (r2 > 0.f) ? r2 : expm1f(r2);
  xoutb[(size_t)v * 128 + lane] = f2bf(r1);
  xoutb[(size_t)v * 128 + 64 + lane] = f2bf(r2);
}

extern "C" void kernel_launch(void* const* d_in, const int* in_sizes, int n_in,
                              void* d_out, int out_size, void* d_ws,
                              size_t ws_size, hipStream_t stream) {
  const float* x = (const float*)d_in[0];
  const int* eidx = (const int*)d_in[1];
  const float* lin_in_w = (const float*)d_in[2];
  const float* lin_in_b = (const float*)d_in[3];
  const float* c0w1 = (const float*)d_in[4];
  const float* c0b1 = (const float*)d_in[5];
  const float* c0w2 = (const float*)d_in[6];
  const float* c0b2 = (const float*)d_in[7];
  const float* c0eps = (const float*)d_in[8];
  const float* c1w1 = (const float*)d_in[9];
  const float* c1b1 = (const float*)d_in[10];
  const float* c1w2 = (const float*)d_in[11];
  const float* c1b2 = (const float*)d_in[12];
  const float* c1eps = (const float*)d_in[13];
  const float* lout_w = (const float*)d_in[14];
  const float* lout_b = (const float*)d_in[15];
  float* out = (float*)d_out;

  int N = in_sizes[0] / 128;
  int E = in_sizes[1] / 2;
  int Npad = N + 64;

  char* ws = (char*)d_ws;
  size_t szHb = (size_t)Npad * 128 * 2;
  size_t szPb = (size_t)Npad * 64 * 2;
  u16* Xb = (u16*)ws;
  u16* Hb = (u16*)(ws + szHb);
  u16* H2b = (u16*)(ws + 2 * szHb);
  u16* Pb = (u16*)(ws + 3 * szHb);
  u16* Qb = (u16*)(ws + 3 * szHb + szPb);
  u16* WTin = (u16*)(ws + 3 * szHb + 2 * szPb);
  u16* WT1a = WTin + 16384;
  u16* WT1b = WT1a + 16384;
  u16* WTout = WT1b + 16384;
  u16* W2Ta = WTout + 8192;
  u16* W2Tb = W2Ta + 2048;
  float* B1pa = (float*)(W2Tb + 2048);
  float* B1pb = B1pa + 128;
  char* ip = (char*)(B1pb + 128);
  int* cnt = (int*)ip;                                  // N
  u16* bucket = (u16*)(ip + 4 * (size_t)(N + 64));      // N*64 u16

  dim3 blk(256);
  int gN = (N + 63) / 64;
  int gE = (E + 255) / 256;

  // fused prep
  k_prep<<<(N * 32 + 255) / 256, blk, 0, stream>>>(
      x, Xb, cnt, N * 32, N, lin_in_w, c0w1, c1w1, lout_w, c0w2, c1w2, c0b1,
      c1b1, WTin, WT1a, WT1b, WTout, W2Ta, W2Tb, B1pa, B1pb,
      (unsigned*)bucket);

  // MERGED: h0 GEMM (2*gN blocks) + bucket fill (gE blocks)
  k_h0_fill<<<2 * gN + gE, blk, 0, stream>>>(Xb, WTin, lin_in_b, Hb, N, gN,
                                             eidx, cnt, bucket, E);

  u16* curb = Hb;
  u16* nxtb = H2b;
  for (int layer = 0; layer < 2; ++layer) {
    const u16* wt1 = layer ? WT1b : WT1a;
    const u16* w2t = layer ? W2Tb : W2Ta;
    const float* b1p = layer ? B1pb : B1pa;
    const float* b2 = layer ? c1b2 : c0b2;
    const float* ep = layer ? c1eps : c0eps;
    // pq = h @ W1p + [0|b1]  (split epilogue: Pb dense 2.5MB + Qb)
    k_gemm_mfma<<<dim3(gN, 2), blk, 0, stream>>>(curb, wt1, b1p, nullptr, Pb,
                                                 Qb, N, 128);
    k_conv<<<N, dim3(64), 0, stream>>>(curb, Pb, Qb, w2t, b2, cnt, bucket, ep,
                                       nxtb, N);
    u16* tb = curb; curb = nxtb; nxtb = tb;
  }

  // out = h @ lin_out_w + b
  k_gemm_mfma<<<dim3(gN, 2), blk, 0, stream>>>(curb, WTout, lout_b, out,
                                               nullptr, nullptr, N, 64);
}